// Round 13
// baseline (722.816 us; speedup 1.0000x reference)
//
#include <hip/hip_runtime.h>
#include <hip/hip_fp16.h>
#include <math.h>

#define N_NODES 100000
#define N_BASE  5000
#define N_EDGES 3200000
#define NBKT    391       // dest buckets of 256 nodes; also = ceil(E/8192) edge blocks
#define CAPB    9472      // csr slots per bucket (mean 8184, sigma 90 -> +14 sigma)

// ---------------------------------------------------------------------------
// k_initg: gcur[b] = b*CAPB, bins = 0
// ---------------------------------------------------------------------------
__global__ __launch_bounds__(512) void k_initg(int* __restrict__ gcur, float* __restrict__ bins) {
    int t = threadIdx.x;
    if (t < NBKT) gcur[t] = t * CAPB;
    if (t < 64) bins[t] = 0.0f;
}

// ---------------------------------------------------------------------------
// k_bucket (phase A): 391 blocks x 8192 edges. LDS histogram over 391 dest
// buckets -> LDS scan -> one global chunk reservation per (block,bucket) ->
// direct chunked stores of packed (d&255)<<17 | src.
// ---------------------------------------------------------------------------
__global__ __launch_bounds__(256) void k_bucket(const int* __restrict__ row, const int* __restrict__ col,
                                                int* __restrict__ gcur, unsigned* __restrict__ csr) {
    __shared__ int hist[NBKT], gbase[NBKT], cur[NBKT];
    __shared__ int sc[512];
    int t = threadIdx.x;
    int e0 = blockIdx.x * 8192;
    int cnt = (N_EDGES - e0 < 8192) ? (N_EDGES - e0) : 8192;
    for (int k = t; k < NBKT; k += 256) hist[k] = 0;
    __syncthreads();
    for (int j = t; j < cnt; j += 256) atomicAdd(&hist[col[e0 + j] >> 8], 1);
    __syncthreads();
    // inclusive Hillis scan over 512 slots, 2 per thread
    sc[t] = (t < NBKT) ? hist[t] : 0;
    sc[t + 256] = (t + 256 < NBKT) ? hist[t + 256] : 0;
    __syncthreads();
    for (int off = 1; off < 512; off <<= 1) {
        int v0 = (t >= off) ? sc[t - off] : 0;
        int v1 = sc[t + 256 - off];          // t+256-off >= 0 since off <= 256
        __syncthreads();
        sc[t] += v0;
        sc[t + 256] += v1;
        __syncthreads();
    }
    for (int s = t; s < NBKT; s += 256) {
        cur[s] = sc[s] - hist[s];            // local exclusive offset
        gbase[s] = (hist[s] > 0) ? atomicAdd(&gcur[s], hist[s]) : 0;
    }
    __syncthreads();
    for (int j = t; j < cnt; j += 256) {
        int d = col[e0 + j];
        int s = row[e0 + j];
        int b = d >> 8;
        int slot = atomicAdd(&cur[b], 1);
        int local = slot - (sc[b] - hist[b]);
        csr[gbase[b] + local] = ((unsigned)(d & 255) << 17) | (unsigned)s;
    }
}

// ---------------------------------------------------------------------------
// k_sort (phase B): one block per bucket. LDS counting sort of <= CAPB edges
// by local dest; coalesced write-back of pure-src csr into the bucket's own
// window; emits rs/re (exact runs) and dinv (true degree).
// ---------------------------------------------------------------------------
__global__ __launch_bounds__(256) void k_sort(const int* __restrict__ gcur, unsigned* __restrict__ csr,
                                              int* __restrict__ rs, int* __restrict__ re,
                                              float* __restrict__ dinv) {
    __shared__ unsigned stage[CAPB];
    __shared__ int hist[256], offs[256], cur[256];
    int t = threadIdx.x, b = blockIdx.x;
    int base = b * CAPB;
    int cnt = gcur[b] - base;
    hist[t] = 0;
    for (int j = t; j < cnt; j += 256) stage[j] = csr[base + j];
    __syncthreads();
    for (int j = t; j < cnt; j += 256) atomicAdd(&hist[stage[j] >> 17], 1);
    __syncthreads();
    offs[t] = hist[t];
    __syncthreads();
    for (int off = 1; off < 256; off <<= 1) {
        int v = (t >= off) ? offs[t - off] : 0;
        __syncthreads();
        offs[t] += v;
        __syncthreads();
    }
    int excl = offs[t] - hist[t];
    cur[t] = excl;
    int node = b * 256 + t;
    if (node < N_NODES) {
        rs[node] = base + excl;
        re[node] = base + excl + hist[t];
        dinv[node] = rsqrtf((float)(hist[t] + 1));   // +1 self loop
    }
    __syncthreads();
    for (int j = t; j < cnt; j += 256) {
        unsigned p = stage[j];
        int slot = atomicAdd(&cur[p >> 17], 1);
        csr[base + slot] = p & 0x1FFFFu;             // pure src
    }
}

// ---------------------------------------------------------------------------
// k_ab_h: bb = [x1 | tile(x2)] @ W4^T + b4   (f32, float4 stores)
//         h0 = fp16_rne(dinv * (Wg @ [relu(x1@W1^T+b1) | bb]))  (2x uint4 stores)
//         bins += W3[15:34].bb   (iteration-invariant output part)
// h rows 32B: table 3.2 MB -> L2-resident. Pack fix for R11's store regression.
// ---------------------------------------------------------------------------
__global__ __launch_bounds__(256) void k_ab_h(const float* __restrict__ x1, const float* __restrict__ x2,
                                              const float* __restrict__ W1, const float* __restrict__ b1,
                                              const float* __restrict__ W4, const float* __restrict__ b4,
                                              const float* __restrict__ Wg, const float* __restrict__ W3,
                                              const float* __restrict__ dinv,
                                              float* __restrict__ bb, __half* __restrict__ h0,
                                              float* __restrict__ bins) {
    __shared__ float sW1[225], sb1[15], sW4[361], sb4[19], sWg[510], sW3b[19];
    for (int t = threadIdx.x; t < 225; t += 256) sW1[t] = W1[t];
    for (int t = threadIdx.x; t < 361; t += 256) sW4[t] = W4[t];
    for (int t = threadIdx.x; t < 510; t += 256) sWg[t] = Wg[t];
    if (threadIdx.x < 15) sb1[threadIdx.x] = b1[threadIdx.x];
    if (threadIdx.x < 19) { sb4[threadIdx.x] = b4[threadIdx.x]; sW3b[threadIdx.x] = W3[15 + threadIdx.x]; }
    __syncthreads();
    int i = blockIdx.x * 256 + threadIdx.x;
    bool valid = i < N_NODES;
    int ii = valid ? i : 0;
    float x[15];
#pragma unroll
    for (int k = 0; k < 15; k++) x[k] = x1[(size_t)ii * 15 + k];
    float xt[4];
    int ib = ii % N_BASE;
#pragma unroll
    for (int k = 0; k < 4; k++) xt[k] = x2[(size_t)ib * 4 + k];
    float in[34];
    float bp = 0.0f;
#pragma unroll
    for (int o = 0; o < 19; o++) {
        float s = sb4[o];
#pragma unroll
        for (int k = 0; k < 15; k++) s += x[k] * sW4[o * 19 + k];
#pragma unroll
        for (int k = 0; k < 4; k++) s += xt[k] * sW4[o * 19 + 15 + k];
        in[15 + o] = s;
        bp += s * sW3b[o];
    }
#pragma unroll
    for (int o = 0; o < 15; o++) {
        float s = sb1[o];
#pragma unroll
        for (int k = 0; k < 15; k++) s += x[k] * sW1[o * 15 + k];
        in[o] = fmaxf(s, 0.0f);
    }
    float dn = dinv[ii];
    if (valid) {
        float4* bbp = (float4*)(bb + (size_t)ii * 20);
        bbp[0] = make_float4(in[15], in[16], in[17], in[18]);
        bbp[1] = make_float4(in[19], in[20], in[21], in[22]);
        bbp[2] = make_float4(in[23], in[24], in[25], in[26]);
        bbp[3] = make_float4(in[27], in[28], in[29], in[30]);
        bbp[4] = make_float4(in[31], in[32], in[33], 0.0f);   // [19] pad, never consumed
        union { ushort u16[16]; uint4 v4[2]; } hp;
#pragma unroll
        for (int o = 0; o < 15; o++) {
            float s = 0.0f;
#pragma unroll
            for (int k = 0; k < 34; k++) s += in[k] * sWg[o * 34 + k];
            hp.u16[o] = __half_as_ushort(__float2half_rn(s * dn));
        }
        hp.u16[15] = 0;
        uint4* hdst = (uint4*)(h0 + (size_t)ii * 16);
        hdst[0] = hp.v4[0];
        hdst[1] = hp.v4[1];
    }
    float val = valid ? bp : 0.0f;
#pragma unroll
    for (int off = 32; off > 0; off >>= 1) val += __shfl_down(val, off, 64);
    __shared__ float wsum[4];
    if ((threadIdx.x & 63) == 0) wsum[threadIdx.x >> 6] = val;
    __syncthreads();
    if (threadIdx.x == 0) atomicAdd(&bins[blockIdx.x & 63], wsum[0] + wsum[1] + wsum[2] + wsum[3]);
}

// ---------------------------------------------------------------------------
// k_gather: R12 structure (1024 threads, 16 waves = 16 nodes/block) with
// fp16 h tables (R11 numerics, absmax 0.0 measured). Per 64-edge chunk:
// pre-shuffle indices, 2 groups of 8 independent predicated fp16 loads into
// tmp[], acc += tmp[i] in ascending-e0 order.
// ---------------------------------------------------------------------------
__global__ __launch_bounds__(1024) void k_gather(const int* __restrict__ rs, const int* __restrict__ re,
                                                 const unsigned* __restrict__ csr,
                                                 const __half* __restrict__ h_in,
                                                 const float* __restrict__ dinv,
                                                 const float* __restrict__ bb,
                                                 const float* __restrict__ Wg,
                                                 const float* __restrict__ bg,
                                                 const float* __restrict__ W3,
                                                 __half* __restrict__ h_out,
                                                 float* __restrict__ bins, int last) {
    __shared__ float sWg[544], sbg[16], sW3[16];
    __shared__ float ws2[16];
    int t = threadIdx.x;
    for (int k = t; k < 544; k += 1024) sWg[k] = (k < 510) ? Wg[k] : 0.0f;
    if (t < 16) { sbg[t] = (t < 15) ? bg[t] : 0.0f; sW3[t] = (t < 15) ? W3[t] : 0.0f; }
    __syncthreads();
    int node = blockIdx.x * 16 + (t >> 6);
    int lane = t & 63, ch = lane & 15, q = lane >> 4;
    int start = rs[node];
    int deg = re[node] - start;
    float hs = __half2float(h_in[(size_t)node * 16 + ch]);   // self row, hoisted
    float acc = 0.0f;
    for (int base = 0; base < deg; base += 64) {
        int rem = deg - base;
        unsigned ce = 0;
        if (lane < rem) ce = csr[start + base + lane];
        int lim = rem < 64 ? rem : 64;
#pragma unroll
        for (int g = 0; g < 2; g++) {
            float tmp[8];
#pragma unroll
            for (int i = 0; i < 8; i++) {
                int e0 = q + 4 * (8 * g + i);
                unsigned p = __shfl(ce, e0, 64);
                tmp[i] = (e0 < lim) ? __half2float(h_in[(size_t)(p & 0x1FFFFu) * 16 + ch]) : 0.0f;
            }
#pragma unroll
            for (int i = 0; i < 8; i++) acc += tmp[i];
        }
    }
    acc += __shfl_xor(acc, 16, 64);
    acc += __shfl_xor(acc, 32, 64);
    float dn = dinv[node];
    float aval = fmaxf(dn * (hs + acc) + sbg[ch], 0.0f);   // a[ch]; ch==15 -> 0
    if (!last) {
        float ink[15];
#pragma unroll
        for (int k = 0; k < 15; k++) ink[k] = __shfl(aval, k, 64);
        const float4* bp4 = (const float4*)(bb + (size_t)node * 20);
        float4 q0 = bp4[0], q1 = bp4[1], q2 = bp4[2], q3 = bp4[3], q4 = bp4[4];
        float bv[19] = {q0.x, q0.y, q0.z, q0.w, q1.x, q1.y, q1.z, q1.w,
                        q2.x, q2.y, q2.z, q2.w, q3.x, q3.y, q3.z, q3.w,
                        q4.x, q4.y, q4.z};
        float s = 0.0f;
#pragma unroll
        for (int k = 0; k < 15; k++) s += ink[k] * sWg[ch * 34 + k];
#pragma unroll
        for (int k = 0; k < 19; k++) s += bv[k] * sWg[ch * 34 + 15 + k];
        if (q == 0) h_out[(size_t)node * 16 + ch] = __float2half_rn(s * dn);  // ch==15: pad -> 0
    } else {
        float c = aval * sW3[ch];
        c += __shfl_xor(c, 8, 64);
        c += __shfl_xor(c, 4, 64);
        c += __shfl_xor(c, 2, 64);
        c += __shfl_xor(c, 1, 64);
        if (lane == 0) ws2[t >> 6] = c;
        __syncthreads();
        if (t == 0) {
            float s = 0.0f;
#pragma unroll
            for (int k = 0; k < 16; k++) s += ws2[k];
            atomicAdd(&bins[blockIdx.x & 63], s);
        }
    }
}

__global__ void k_finalize(const float* __restrict__ bins, const float* __restrict__ b3,
                           float* __restrict__ out) {
    float s = 0.0f;
    for (int k = 0; k < 64; k++) s += bins[k];
    out[0] = tanhf(s * (1.0f / (float)N_NODES) + b3[0]);
}

// ---------------------------------------------------------------------------
extern "C" void kernel_launch(void* const* d_in, const int* in_sizes, int n_in,
                              void* d_out, int out_size, void* d_ws, size_t ws_size,
                              hipStream_t stream) {
    const float* x1 = (const float*)d_in[0];
    const float* x2 = (const float*)d_in[1];
    const int* edges = (const int*)d_in[2];
    const float* W1 = (const float*)d_in[3];
    const float* b1 = (const float*)d_in[4];
    const float* Wg = (const float*)d_in[5];
    const float* bg = (const float*)d_in[6];
    const float* W3 = (const float*)d_in[7];
    const float* b3 = (const float*)d_in[8];
    const float* W4 = (const float*)d_in[9];
    const float* b4 = (const float*)d_in[10];

    const int* row = edges;             // edges[0]
    const int* col = edges + N_EDGES;   // edges[1]

    // workspace layout — ~30.5 MB (proven envelope >= 40.4 MB).
    // h tables fp16 (3.2 MB each, L2-resident); 16B alignment maintained.
    char* ws = (char*)d_ws;
    unsigned* csr  = (unsigned*)ws;                              // NBKT*CAPB  (14.81 MB)
    float*    bb   = (float*)(csr + (size_t)NBKT * CAPB);        // N*20       (8.0 MB)
    __half*   h0   = (__half*)(bb + (size_t)N_NODES * 20);       // N*16 fp16  (3.2 MB)
    __half*   h1   = h0 + (size_t)N_NODES * 16;                  // N*16 fp16  (3.2 MB)
    float*    dinv = (float*)(h1 + (size_t)N_NODES * 16);        // N
    int*      rs   = (int*)(dinv + N_NODES);                     // N
    int*      re   = rs + N_NODES;                               // N
    int*      gcur = re + N_NODES;                               // NBKT
    float*    bins = (float*)(gcur + NBKT);                      // 64

    int gN = (N_NODES + 255) / 256;                              // 391
    int gE = (N_EDGES + 8191) / 8192;                            // 391

    k_initg<<<1, 512, 0, stream>>>(gcur, bins);
    k_bucket<<<gE, 256, 0, stream>>>(row, col, gcur, csr);
    k_sort<<<NBKT, 256, 0, stream>>>(gcur, csr, rs, re, dinv);
    k_ab_h<<<gN, 256, 0, stream>>>(x1, x2, W1, b1, W4, b4, Wg, W3, dinv, bb, h0, bins);
    for (int t = 0; t < 5; t++) {
        const __half* hi = (t & 1) ? h1 : h0;
        __half* ho = (t & 1) ? h0 : h1;
        k_gather<<<N_NODES / 16, 1024, 0, stream>>>(rs, re, csr, hi, dinv, bb, Wg, bg, W3,
                                                    ho, bins, t == 4 ? 1 : 0);
    }
    k_finalize<<<1, 1, 0, stream>>>(bins, b3, (float*)d_out);
}

// Round 14
// 561.678 us; speedup vs baseline: 1.2869x; 1.2869x over previous
//
#include <hip/hip_runtime.h>
#include <math.h>

#define N_NODES 100000
#define N_BASE  5000
#define N_EDGES 3200000
#define NBKT    391       // dest buckets of 256 nodes; also = ceil(E/8192) edge blocks
#define CAPB    9472      // csr slots per bucket (mean 8184, sigma 90 -> +14 sigma)

// ---------------------------------------------------------------------------
// k_initg: gcur[b] = b*CAPB, bins = 0
// ---------------------------------------------------------------------------
__global__ __launch_bounds__(512) void k_initg(int* __restrict__ gcur, float* __restrict__ bins) {
    int t = threadIdx.x;
    if (t < NBKT) gcur[t] = t * CAPB;
    if (t < 64) bins[t] = 0.0f;
}

// ---------------------------------------------------------------------------
// k_bucket (phase A): 391 blocks x 8192 edges. LDS histogram over 391 dest
// buckets -> LDS scan -> one global chunk reservation per (block,bucket) ->
// direct chunked stores of packed (d&255)<<17 | src.
// ---------------------------------------------------------------------------
__global__ __launch_bounds__(256) void k_bucket(const int* __restrict__ row, const int* __restrict__ col,
                                                int* __restrict__ gcur, unsigned* __restrict__ csr) {
    __shared__ int hist[NBKT], gbase[NBKT], cur[NBKT];
    __shared__ int sc[512];
    int t = threadIdx.x;
    int e0 = blockIdx.x * 8192;
    int cnt = (N_EDGES - e0 < 8192) ? (N_EDGES - e0) : 8192;
    for (int k = t; k < NBKT; k += 256) hist[k] = 0;
    __syncthreads();
    for (int j = t; j < cnt; j += 256) atomicAdd(&hist[col[e0 + j] >> 8], 1);
    __syncthreads();
    // inclusive Hillis scan over 512 slots, 2 per thread
    sc[t] = (t < NBKT) ? hist[t] : 0;
    sc[t + 256] = (t + 256 < NBKT) ? hist[t + 256] : 0;
    __syncthreads();
    for (int off = 1; off < 512; off <<= 1) {
        int v0 = (t >= off) ? sc[t - off] : 0;
        int v1 = sc[t + 256 - off];          // t+256-off >= 0 since off <= 256
        __syncthreads();
        sc[t] += v0;
        sc[t + 256] += v1;
        __syncthreads();
    }
    for (int s = t; s < NBKT; s += 256) {
        cur[s] = sc[s] - hist[s];            // local exclusive offset
        gbase[s] = (hist[s] > 0) ? atomicAdd(&gcur[s], hist[s]) : 0;
    }
    __syncthreads();
    for (int j = t; j < cnt; j += 256) {
        int d = col[e0 + j];
        int s = row[e0 + j];
        int b = d >> 8;
        int slot = atomicAdd(&cur[b], 1);
        int local = slot - (sc[b] - hist[b]);
        csr[gbase[b] + local] = ((unsigned)(d & 255) << 17) | (unsigned)s;
    }
}

// ---------------------------------------------------------------------------
// k_sort (phase B): one block per bucket. LDS counting sort of <= CAPB edges
// by local dest; coalesced write-back of pure-src csr into the bucket's own
// window; emits rs/re (exact runs) and dinv (true degree).
// ---------------------------------------------------------------------------
__global__ __launch_bounds__(256) void k_sort(const int* __restrict__ gcur, unsigned* __restrict__ csr,
                                              int* __restrict__ rs, int* __restrict__ re,
                                              float* __restrict__ dinv) {
    __shared__ unsigned stage[CAPB];
    __shared__ int hist[256], offs[256], cur[256];
    int t = threadIdx.x, b = blockIdx.x;
    int base = b * CAPB;
    int cnt = gcur[b] - base;
    hist[t] = 0;
    for (int j = t; j < cnt; j += 256) stage[j] = csr[base + j];
    __syncthreads();
    for (int j = t; j < cnt; j += 256) atomicAdd(&hist[stage[j] >> 17], 1);
    __syncthreads();
    offs[t] = hist[t];
    __syncthreads();
    for (int off = 1; off < 256; off <<= 1) {
        int v = (t >= off) ? offs[t - off] : 0;
        __syncthreads();
        offs[t] += v;
        __syncthreads();
    }
    int excl = offs[t] - hist[t];
    cur[t] = excl;
    int node = b * 256 + t;
    if (node < N_NODES) {
        rs[node] = base + excl;
        re[node] = base + excl + hist[t];
        dinv[node] = rsqrtf((float)(hist[t] + 1));   // +1 self loop
    }
    __syncthreads();
    for (int j = t; j < cnt; j += 256) {
        unsigned p = stage[j];
        int slot = atomicAdd(&cur[p >> 17], 1);
        csr[base + slot] = p & 0x1FFFFu;             // pure src
    }
}

// ---------------------------------------------------------------------------
// k_ab_h (R12 verbatim): bb = [x1 | tile(x2)] @ W4^T + b4  (float4 stores)
//         h0 = dinv * (Wg @ [relu(x1@W1^T+b1) | bb])       (float4 stores)
//         bins += W3[15:34].bb   (iteration-invariant output part)
// ---------------------------------------------------------------------------
__global__ __launch_bounds__(256) void k_ab_h(const float* __restrict__ x1, const float* __restrict__ x2,
                                              const float* __restrict__ W1, const float* __restrict__ b1,
                                              const float* __restrict__ W4, const float* __restrict__ b4,
                                              const float* __restrict__ Wg, const float* __restrict__ W3,
                                              const float* __restrict__ dinv,
                                              float* __restrict__ bb, float* __restrict__ h0,
                                              float* __restrict__ bins) {
    __shared__ float sW1[225], sb1[15], sW4[361], sb4[19], sWg[510], sW3b[19];
    for (int t = threadIdx.x; t < 225; t += 256) sW1[t] = W1[t];
    for (int t = threadIdx.x; t < 361; t += 256) sW4[t] = W4[t];
    for (int t = threadIdx.x; t < 510; t += 256) sWg[t] = Wg[t];
    if (threadIdx.x < 15) sb1[threadIdx.x] = b1[threadIdx.x];
    if (threadIdx.x < 19) { sb4[threadIdx.x] = b4[threadIdx.x]; sW3b[threadIdx.x] = W3[15 + threadIdx.x]; }
    __syncthreads();
    int i = blockIdx.x * 256 + threadIdx.x;
    bool valid = i < N_NODES;
    int ii = valid ? i : 0;
    float x[15];
#pragma unroll
    for (int k = 0; k < 15; k++) x[k] = x1[(size_t)ii * 15 + k];
    float xt[4];
    int ib = ii % N_BASE;
#pragma unroll
    for (int k = 0; k < 4; k++) xt[k] = x2[(size_t)ib * 4 + k];
    float in[34];
    float bp = 0.0f;
#pragma unroll
    for (int o = 0; o < 19; o++) {
        float s = sb4[o];
#pragma unroll
        for (int k = 0; k < 15; k++) s += x[k] * sW4[o * 19 + k];
#pragma unroll
        for (int k = 0; k < 4; k++) s += xt[k] * sW4[o * 19 + 15 + k];
        in[15 + o] = s;
        bp += s * sW3b[o];
    }
#pragma unroll
    for (int o = 0; o < 15; o++) {
        float s = sb1[o];
#pragma unroll
        for (int k = 0; k < 15; k++) s += x[k] * sW1[o * 15 + k];
        in[o] = fmaxf(s, 0.0f);
    }
    float dn = dinv[ii];
    if (valid) {
        float4* bbp = (float4*)(bb + (size_t)ii * 20);
        bbp[0] = make_float4(in[15], in[16], in[17], in[18]);
        bbp[1] = make_float4(in[19], in[20], in[21], in[22]);
        bbp[2] = make_float4(in[23], in[24], in[25], in[26]);
        bbp[3] = make_float4(in[27], in[28], in[29], in[30]);
        bbp[4] = make_float4(in[31], in[32], in[33], 0.0f);   // [19] pad, never consumed
        float hv[15];
#pragma unroll
        for (int o = 0; o < 15; o++) {
            float s = 0.0f;
#pragma unroll
            for (int k = 0; k < 34; k++) s += in[k] * sWg[o * 34 + k];
            hv[o] = s * dn;
        }
        float4* hp = (float4*)(h0 + (size_t)ii * 16);
        hp[0] = make_float4(hv[0], hv[1], hv[2], hv[3]);
        hp[1] = make_float4(hv[4], hv[5], hv[6], hv[7]);
        hp[2] = make_float4(hv[8], hv[9], hv[10], hv[11]);
        hp[3] = make_float4(hv[12], hv[13], hv[14], 0.0f);
    }
    float val = valid ? bp : 0.0f;
#pragma unroll
    for (int off = 32; off > 0; off >>= 1) val += __shfl_down(val, off, 64);
    __shared__ float wsum[4];
    if ((threadIdx.x & 63) == 0) wsum[threadIdx.x >> 6] = val;
    __syncthreads();
    if (threadIdx.x == 0) atomicAdd(&bins[blockIdx.x & 63], wsum[0] + wsum[1] + wsum[2] + wsum[3]);
}

// ---------------------------------------------------------------------------
// k_gather: R12 structure (1024 threads, f32 h) with the two tmp[8] groups
// fused into one tmp[16] group: 16 independent predicated loads in flight
// per wave before any consumption. Flattened e0 = q+4i, i=0..15 is the exact
// concatenation of the old g=0,g=1 sequences; acc += tmp[i] in the same
// ascending order -> bit-identical summation to R12.
// ---------------------------------------------------------------------------
__global__ __launch_bounds__(1024) void k_gather(const int* __restrict__ rs, const int* __restrict__ re,
                                                 const unsigned* __restrict__ csr,
                                                 const float* __restrict__ h_in,
                                                 const float* __restrict__ dinv,
                                                 const float* __restrict__ bb,
                                                 const float* __restrict__ Wg,
                                                 const float* __restrict__ bg,
                                                 const float* __restrict__ W3,
                                                 float* __restrict__ h_out,
                                                 float* __restrict__ bins, int last) {
    __shared__ float sWg[544], sbg[16], sW3[16];
    __shared__ float ws2[16];
    int t = threadIdx.x;
    for (int k = t; k < 544; k += 1024) sWg[k] = (k < 510) ? Wg[k] : 0.0f;
    if (t < 16) { sbg[t] = (t < 15) ? bg[t] : 0.0f; sW3[t] = (t < 15) ? W3[t] : 0.0f; }
    __syncthreads();
    int node = blockIdx.x * 16 + (t >> 6);
    int lane = t & 63, ch = lane & 15, q = lane >> 4;
    int start = rs[node];
    int deg = re[node] - start;
    float hs = h_in[(size_t)node * 16 + ch];   // self row, hoisted for overlap
    float acc = 0.0f;
    for (int base = 0; base < deg; base += 64) {
        int rem = deg - base;
        unsigned ce = 0;
        if (lane < rem) ce = csr[start + base + lane];
        int lim = rem < 64 ? rem : 64;
        float tmp[16];
#pragma unroll
        for (int i = 0; i < 16; i++) {
            int e0 = q + 4 * i;
            unsigned p = __shfl(ce, e0, 64);
            tmp[i] = (e0 < lim) ? h_in[(size_t)(p & 0x1FFFFu) * 16 + ch] : 0.0f;
        }
#pragma unroll
        for (int i = 0; i < 16; i++) acc += tmp[i];
    }
    acc += __shfl_xor(acc, 16, 64);
    acc += __shfl_xor(acc, 32, 64);
    float dn = dinv[node];
    float aval = fmaxf(dn * (hs + acc) + sbg[ch], 0.0f);   // a[ch]; ch==15 -> 0
    if (!last) {
        float ink[15];
#pragma unroll
        for (int k = 0; k < 15; k++) ink[k] = __shfl(aval, k, 64);
        const float4* bp4 = (const float4*)(bb + (size_t)node * 20);
        float4 q0 = bp4[0], q1 = bp4[1], q2 = bp4[2], q3 = bp4[3], q4 = bp4[4];
        float bv[19] = {q0.x, q0.y, q0.z, q0.w, q1.x, q1.y, q1.z, q1.w,
                        q2.x, q2.y, q2.z, q2.w, q3.x, q3.y, q3.z, q3.w,
                        q4.x, q4.y, q4.z};
        float s = 0.0f;
#pragma unroll
        for (int k = 0; k < 15; k++) s += ink[k] * sWg[ch * 34 + k];
#pragma unroll
        for (int k = 0; k < 19; k++) s += bv[k] * sWg[ch * 34 + 15 + k];
        if (q == 0) h_out[(size_t)node * 16 + ch] = s * dn;   // ch==15 row: sWg pad -> 0
    } else {
        float c = aval * sW3[ch];
        c += __shfl_xor(c, 8, 64);
        c += __shfl_xor(c, 4, 64);
        c += __shfl_xor(c, 2, 64);
        c += __shfl_xor(c, 1, 64);
        if (lane == 0) ws2[t >> 6] = c;
        __syncthreads();
        if (t == 0) {
            float s = 0.0f;
#pragma unroll
            for (int k = 0; k < 16; k++) s += ws2[k];
            atomicAdd(&bins[blockIdx.x & 63], s);
        }
    }
}

__global__ void k_finalize(const float* __restrict__ bins, const float* __restrict__ b3,
                           float* __restrict__ out) {
    float s = 0.0f;
    for (int k = 0; k < 64; k++) s += bins[k];
    out[0] = tanhf(s * (1.0f / (float)N_NODES) + b3[0]);
}

// ---------------------------------------------------------------------------
extern "C" void kernel_launch(void* const* d_in, const int* in_sizes, int n_in,
                              void* d_out, int out_size, void* d_ws, size_t ws_size,
                              hipStream_t stream) {
    const float* x1 = (const float*)d_in[0];
    const float* x2 = (const float*)d_in[1];
    const int* edges = (const int*)d_in[2];
    const float* W1 = (const float*)d_in[3];
    const float* b1 = (const float*)d_in[4];
    const float* Wg = (const float*)d_in[5];
    const float* bg = (const float*)d_in[6];
    const float* W3 = (const float*)d_in[7];
    const float* b3 = (const float*)d_in[8];
    const float* W4 = (const float*)d_in[9];
    const float* b4 = (const float*)d_in[10];

    const int* row = edges;             // edges[0]
    const int* col = edges + N_EDGES;   // edges[1]

    // workspace layout — ~36.9 MB (proven envelope >= 40.4 MB).
    char* ws = (char*)d_ws;
    unsigned* csr  = (unsigned*)ws;                              // NBKT*CAPB  (14.81 MB)
    float*    bb   = (float*)(csr + (size_t)NBKT * CAPB);        // N*20       (8.0 MB)
    float*    h0   = bb + (size_t)N_NODES * 20;                  // N*16       (6.4 MB)
    float*    h1   = h0 + (size_t)N_NODES * 16;                  // N*16       (6.4 MB)
    float*    dinv = h1 + (size_t)N_NODES * 16;                  // N
    int*      rs   = (int*)(dinv + N_NODES);                     // N
    int*      re   = rs + N_NODES;                               // N
    int*      gcur = re + N_NODES;                               // NBKT
    float*    bins = (float*)(gcur + NBKT);                      // 64

    int gN = (N_NODES + 255) / 256;                              // 391
    int gE = (N_EDGES + 8191) / 8192;                            // 391

    k_initg<<<1, 512, 0, stream>>>(gcur, bins);
    k_bucket<<<gE, 256, 0, stream>>>(row, col, gcur, csr);
    k_sort<<<NBKT, 256, 0, stream>>>(gcur, csr, rs, re, dinv);
    k_ab_h<<<gN, 256, 0, stream>>>(x1, x2, W1, b1, W4, b4, Wg, W3, dinv, bb, h0, bins);
    for (int t = 0; t < 5; t++) {
        const float* hi = (t & 1) ? h1 : h0;
        float* ho = (t & 1) ? h0 : h1;
        k_gather<<<N_NODES / 16, 1024, 0, stream>>>(rs, re, csr, hi, dinv, bb, Wg, bg, W3,
                                                    ho, bins, t == 4 ? 1 : 0);
    }
    k_finalize<<<1, 1, 0, stream>>>(bins, b3, (float*)d_out);
}